// Round 1
// baseline (1058.630 us; speedup 1.0000x reference)
//
#include <hip/hip_runtime.h>

#define N_NODES 50000
#define N_EDGES 800000
#define NEG_SLOPE 0.2f
#define LN_EPS 1e-5f

// monotone float<->uint encoding for atomicMax on floats
__device__ __forceinline__ unsigned enc_f32(float f) {
    unsigned u = __float_as_uint(f);
    return (u & 0x80000000u) ? ~u : (u | 0x80000000u);
}
__device__ __forceinline__ float dec_f32(unsigned e) {
    unsigned u = (e & 0x80000000u) ? (e & 0x7FFFFFFFu) : ~e;
    return __uint_as_float(u);
}

// init smax to enc(-inf)
__global__ __launch_bounds__(256) void k0_init(unsigned* __restrict__ smax) {
    int i = blockIdx.x * 256 + threadIdx.x;
    if (i < N_NODES * 4) smax[i] = 0x007FFFFFu;  // enc(-inf)
}

// K1: wv = h @ W_node + b_node (N x 256), alpha_u/v[n,h] = <wv[n,h,:], att[h,:]>
// block 256 threads; thread t owns output column t; W column cached in 64 VGPRs.
// h row elements are wave-uniform -> scalar loads.
__global__ __launch_bounds__(256) void k1_wv(
    const float* __restrict__ h, const float* __restrict__ Wn,
    const float* __restrict__ bn, const float* __restrict__ att,
    float* __restrict__ wv, float* __restrict__ alpha_u, float* __restrict__ alpha_v)
{
    const int t = threadIdx.x;
    const int w = t >> 6, lane = t & 63;
    float wcol[64];
#pragma unroll
    for (int k = 0; k < 64; ++k) wcol[k] = Wn[k * 256 + t];
    const float bcol = bn[t];
    const float au = att[w * 128 + lane];
    const float av = att[w * 128 + 64 + lane];
    for (int n = blockIdx.x; n < N_NODES; n += gridDim.x) {
        const float* __restrict__ hrow = h + n * 64;
        float acc0 = bcol, acc1 = 0.f;
#pragma unroll
        for (int k = 0; k < 64; k += 2) {
            acc0 = fmaf(hrow[k], wcol[k], acc0);
            acc1 = fmaf(hrow[k + 1], wcol[k + 1], acc1);
        }
        float acc = acc0 + acc1;
        wv[n * 256 + t] = acc;
        float ru = acc * au, rv = acc * av;
#pragma unroll
        for (int off = 32; off; off >>= 1) {
            ru += __shfl_xor(ru, off);
            rv += __shfl_xor(rv, off);
        }
        if (lane == 0) {
            alpha_u[n * 4 + w] = ru;
            alpha_v[n * 4 + w] = rv;
        }
    }
}

// K2: per-edge logit = leaky(alpha_u[src]+alpha_v[dst]); segment-max via atomicMax
__global__ __launch_bounds__(256) void k2_logit(
    const int* __restrict__ src, const int* __restrict__ dst,
    const float* __restrict__ alpha_u, const float* __restrict__ alpha_v,
    float* __restrict__ logit, unsigned* __restrict__ smax)
{
    int e = blockIdx.x * 256 + threadIdx.x;
    if (e >= N_EDGES) return;
    int s = src[e], d = dst[e];
    const float4 au = *(const float4*)(alpha_u + (size_t)s * 4);
    const float4 av = *(const float4*)(alpha_v + (size_t)d * 4);
    float lg[4] = {au.x + av.x, au.y + av.y, au.z + av.z, au.w + av.w};
#pragma unroll
    for (int hh = 0; hh < 4; ++hh) {
        float v = lg[hh];
        v = v > 0.f ? v : NEG_SLOPE * v;
        lg[hh] = v;
        atomicMax(smax + (size_t)d * 4 + hh, enc_f32(v));
    }
    *(float4*)(logit + (size_t)e * 4) = make_float4(lg[0], lg[1], lg[2], lg[3]);
}

// K3: one wave per edge; ex = exp(logit - smax[dst]); atomicAdd denom and agg += ex*wv[src]
__global__ __launch_bounds__(256) void k3_agg(
    const int* __restrict__ src, const int* __restrict__ dst,
    const float* __restrict__ logit, const unsigned* __restrict__ smax,
    const float* __restrict__ wv, float* __restrict__ denom, float* __restrict__ agg)
{
    const int lane = threadIdx.x & 63;
    const int wglobal = __builtin_amdgcn_readfirstlane((int)((blockIdx.x * 256 + threadIdx.x) >> 6));
    const int nwaves = (gridDim.x * 256) >> 6;
    for (int e = wglobal; e < N_EDGES; e += nwaves) {
        const int s = src[e], d = dst[e];
        const float* __restrict__ lg = logit + (size_t)e * 4;
        const unsigned* __restrict__ sm = smax + (size_t)d * 4;
        float exv[4];
#pragma unroll
        for (int hh = 0; hh < 4; ++hh) exv[hh] = __expf(lg[hh] - dec_f32(sm[hh]));
        if (lane < 4) atomicAdd(denom + (size_t)d * 4 + lane, exv[lane]);
#pragma unroll
        for (int hh = 0; hh < 4; ++hh) {
            float uu = wv[(size_t)s * 256 + hh * 64 + lane];
            atomicAdd(agg + (size_t)d * 256 + hh * 64 + lane, exv[hh] * uu);
        }
    }
}

// K4: h_new = (agg/denom) @ W_scale + bias; x = h_new + h; LN; relu
// wave w owns k-range [64w,64w+64) (== head w); W_scale block cached in 64 VGPRs.
__global__ __launch_bounds__(256) void k4_out(
    const float* __restrict__ agg, const float* __restrict__ denom,
    const float* __restrict__ Ws, const float* __restrict__ bias,
    const float* __restrict__ h, const float* __restrict__ gamma_,
    const float* __restrict__ beta_, float* __restrict__ out)
{
    __shared__ float part[256];
    const int t = threadIdx.x;
    const int w = __builtin_amdgcn_readfirstlane(t >> 6);
    const int c = t & 63;
    float wreg[64];
#pragma unroll
    for (int k = 0; k < 64; ++k) wreg[k] = Ws[(size_t)(w * 64 + k) * 64 + c];
    const float bc = bias[c], gc = gamma_[c], btc = beta_[c];
    for (int n = blockIdx.x; n < N_NODES; n += gridDim.x) {
        const float den = denom[(size_t)n * 4 + w];
        const float inv = 1.0f / fmaxf(den, 1e-16f);
        const float* __restrict__ arow = agg + (size_t)n * 256 + w * 64;
        float p0 = 0.f, p1 = 0.f;
#pragma unroll
        for (int k = 0; k < 64; k += 2) {
            p0 = fmaf(arow[k], wreg[k], p0);
            p1 = fmaf(arow[k + 1], wreg[k + 1], p1);
        }
        part[t] = (p0 + p1) * inv;
        __syncthreads();
        if (w == 0) {
            float x = part[c] + part[64 + c] + part[128 + c] + part[192 + c] + bc + h[(size_t)n * 64 + c];
            float mu = x;
#pragma unroll
            for (int off = 32; off; off >>= 1) mu += __shfl_xor(mu, off);
            mu *= (1.0f / 64.0f);
            const float xm = x - mu;
            float v2 = xm * xm;
#pragma unroll
            for (int off = 32; off; off >>= 1) v2 += __shfl_xor(v2, off);
            v2 *= (1.0f / 64.0f);
            const float xn = xm * rsqrtf(v2 + LN_EPS);
            out[(size_t)n * 64 + c] = fmaxf(xn * gc + btc, 0.0f);
        }
        __syncthreads();
    }
}

extern "C" void kernel_launch(void* const* d_in, const int* in_sizes, int n_in,
                              void* d_out, int out_size, void* d_ws, size_t ws_size,
                              hipStream_t stream) {
    const float* h      = (const float*)d_in[0];
    const int*   src    = (const int*)d_in[1];
    const int*   dst    = (const int*)d_in[2];
    const float* Wn     = (const float*)d_in[3];
    const float* bn     = (const float*)d_in[4];
    const float* att    = (const float*)d_in[5];
    const float* Ws     = (const float*)d_in[6];
    const float* bias   = (const float*)d_in[7];
    const float* gamma_ = (const float*)d_in[8];
    const float* beta_  = (const float*)d_in[9];
    float* out = (float*)d_out;

    char* ws = (char*)d_ws;
    size_t off = 0;
    float* wv = (float*)(ws + off);      off += (size_t)N_NODES * 256 * 4;   // 51.2 MB
    float* agg = (float*)(ws + off);     off += (size_t)N_NODES * 256 * 4;   // 51.2 MB
    float* denom = (float*)(ws + off);   off += (size_t)N_NODES * 4 * 4;     // 0.8 MB (contiguous with agg for one memset)
    float* alpha_u = (float*)(ws + off); off += (size_t)N_NODES * 4 * 4;
    float* alpha_v = (float*)(ws + off); off += (size_t)N_NODES * 4 * 4;
    float* logit = (float*)(ws + off);   off += (size_t)N_EDGES * 4 * 4;     // 12.8 MB
    unsigned* smax = (unsigned*)(ws + off); off += (size_t)N_NODES * 4 * 4;

    // zero agg + denom (contiguous), init smax to enc(-inf)
    hipMemsetAsync(agg, 0, ((size_t)N_NODES * 256 + (size_t)N_NODES * 4) * 4, stream);
    k0_init<<<(N_NODES * 4 + 255) / 256, 256, 0, stream>>>(smax);

    k1_wv<<<1024, 256, 0, stream>>>(h, Wn, bn, att, wv, alpha_u, alpha_v);
    k2_logit<<<(N_EDGES + 255) / 256, 256, 0, stream>>>(src, dst, alpha_u, alpha_v, logit, smax);
    k3_agg<<<2048, 256, 0, stream>>>(src, dst, logit, smax, wv, denom, agg);
    k4_out<<<2048, 256, 0, stream>>>(agg, denom, Ws, bias, h, gamma_, beta_, out);
}

// Round 2
// 730.628 us; speedup vs baseline: 1.4489x; 1.4489x over previous
//
#include <hip/hip_runtime.h>

#define N_NODES 50000
#define N_EDGES 800000
#define NEG_SLOPE 0.2f
#define LN_EPS 1e-5f
#define NB_SCAN 196  // ceil(N_NODES/256)

// ---------------- K1: wv = h @ W_node + b; alpha_u/v[n,h] = <wv[n,h,:], att[h,:]> ----------------
__global__ __launch_bounds__(256) void k1_wv(
    const float* __restrict__ h, const float* __restrict__ Wn,
    const float* __restrict__ bn, const float* __restrict__ att,
    float* __restrict__ wv, float* __restrict__ alpha_u, float* __restrict__ alpha_v)
{
    const int t = threadIdx.x;
    const int w = t >> 6, lane = t & 63;
    float wcol[64];
#pragma unroll
    for (int k = 0; k < 64; ++k) wcol[k] = Wn[k * 256 + t];
    const float bcol = bn[t];
    const float au = att[w * 128 + lane];
    const float av = att[w * 128 + 64 + lane];
    for (int n = blockIdx.x; n < N_NODES; n += gridDim.x) {
        const float* __restrict__ hrow = h + (size_t)n * 64;
        float acc0 = bcol, acc1 = 0.f;
#pragma unroll
        for (int k = 0; k < 64; k += 2) {
            acc0 = fmaf(hrow[k], wcol[k], acc0);
            acc1 = fmaf(hrow[k + 1], wcol[k + 1], acc1);
        }
        float acc = acc0 + acc1;
        wv[(size_t)n * 256 + t] = acc;
        float ru = acc * au, rv = acc * av;
#pragma unroll
        for (int off = 32; off; off >>= 1) {
            ru += __shfl_xor(ru, off);
            rv += __shfl_xor(rv, off);
        }
        if (lane == 0) {
            alpha_u[n * 4 + w] = ru;
            alpha_v[n * 4 + w] = rv;
        }
    }
}

// ---------------- CSR build ----------------
__global__ __launch_bounds__(256) void k_deg(const int* __restrict__ dst, int* __restrict__ deg) {
    int e = blockIdx.x * 256 + threadIdx.x;
    if (e < N_EDGES) atomicAdd(&deg[dst[e]], 1);
}

__device__ __forceinline__ int wave_incl_scan(int x, int lane) {
#pragma unroll
    for (int off = 1; off < 64; off <<= 1) {
        int y = __shfl_up(x, off);
        if (lane >= off) x += y;
    }
    return x;
}

// per-256-block exclusive scan; write block totals
__global__ __launch_bounds__(256) void k_scan1(const int* __restrict__ deg,
                                               int* __restrict__ rowptr, int* __restrict__ bsum) {
    __shared__ int wsum[4];
    const int t = threadIdx.x, lane = t & 63, w = t >> 6;
    const int i = blockIdx.x * 256 + t;
    int x = (i < N_NODES) ? deg[i] : 0;
    int incl = wave_incl_scan(x, lane);
    if (lane == 63) wsum[w] = incl;
    __syncthreads();
    int pre = 0;
    for (int ww = 0; ww < w; ++ww) pre += wsum[ww];
    if (i < N_NODES) rowptr[i] = pre + incl - x;
    if (t == 255) bsum[blockIdx.x] = pre + incl;
}

// single-block scan of the 196 block sums -> exclusive offsets
__global__ __launch_bounds__(256) void k_scan2(const int* __restrict__ bsum, int* __restrict__ boff) {
    __shared__ int wsum[4];
    const int t = threadIdx.x, lane = t & 63, w = t >> 6;
    int x = (t < NB_SCAN) ? bsum[t] : 0;
    int incl = wave_incl_scan(x, lane);
    if (lane == 63) wsum[w] = incl;
    __syncthreads();
    int pre = 0;
    for (int ww = 0; ww < w; ++ww) pre += wsum[ww];
    if (t < NB_SCAN) boff[t] = pre + incl - x;
}

// add block offsets; produce cursor copy; rowptr[N] = E
__global__ __launch_bounds__(256) void k_scan3(int* __restrict__ rowptr, const int* __restrict__ boff,
                                               int* __restrict__ cursor) {
    const int i = blockIdx.x * 256 + threadIdx.x;
    if (i < N_NODES) {
        int v = rowptr[i] + boff[blockIdx.x];
        rowptr[i] = v;
        cursor[i] = v;
    }
    if (i == 0) rowptr[N_NODES] = N_EDGES;
}

__global__ __launch_bounds__(256) void k_scatter(const int* __restrict__ src, const int* __restrict__ dst,
                                                 int* __restrict__ cursor, int* __restrict__ csr_src) {
    int e = blockIdx.x * 256 + threadIdx.x;
    if (e < N_EDGES) {
        int pos = atomicAdd(&cursor[dst[e]], 1);
        csr_src[pos] = src[e];
    }
}

// ---------------- fused K3+K4: per-node softmax-aggregate + output GEMM + LN ----------------
__global__ __launch_bounds__(256) void k_node(
    const int* __restrict__ rowptr, const int* __restrict__ csr_src,
    const float* __restrict__ alpha_u, const float* __restrict__ alpha_v,
    const float* __restrict__ wv, const float* __restrict__ Ws,
    const float* __restrict__ bias, const float* __restrict__ h,
    const float* __restrict__ gamma_, const float* __restrict__ beta_,
    float* __restrict__ out)
{
    __shared__ float aggs[256];
    __shared__ float part[256];
    const int t = threadIdx.x;
    const int w = __builtin_amdgcn_readfirstlane(t >> 6);
    const int c = t & 63;
    float wreg[64];
#pragma unroll
    for (int k = 0; k < 64; ++k) wreg[k] = Ws[(size_t)(w * 64 + k) * 64 + c];
    const float bc = bias[c], gc = gamma_[c], btc = beta_[c];

    for (int n = blockIdx.x; n < N_NODES; n += gridDim.x) {
        const int r0 = rowptr[n], r1 = rowptr[n + 1];
        const float avw = alpha_v[n * 4 + w];
        // pass 1: per-head max (redundant across lanes -> no communication)
        float m = -INFINITY;
        for (int j = r0; j < r1; ++j) {
            const int s = csr_src[j];
            float lg = alpha_u[s * 4 + w] + avw;
            lg = lg > 0.f ? lg : NEG_SLOPE * lg;
            m = fmaxf(m, lg);
        }
        // pass 2: accumulate
        float acc = 0.f, den = 0.f;
        int sN = (r0 < r1) ? csr_src[r0] : 0;
        for (int j = r0; j < r1; ++j) {
            const int s = sN;
            if (j + 1 < r1) sN = csr_src[j + 1];
            float lg = alpha_u[s * 4 + w] + avw;
            lg = lg > 0.f ? lg : NEG_SLOPE * lg;
            const float ex = __expf(lg - m);
            const float uu = wv[(size_t)s * 256 + t];
            den += ex;
            acc = fmaf(ex, uu, acc);
        }
        const float inv = 1.0f / fmaxf(den, 1e-16f);
        aggs[t] = acc * inv;
        __syncthreads();
        float p = 0.f;
#pragma unroll
        for (int k = 0; k < 64; ++k) p = fmaf(aggs[w * 64 + k], wreg[k], p);
        part[t] = p;
        __syncthreads();
        if (w == 0) {
            float x = part[c] + part[64 + c] + part[128 + c] + part[192 + c] + bc + h[(size_t)n * 64 + c];
            float mu = x;
#pragma unroll
            for (int off = 32; off; off >>= 1) mu += __shfl_xor(mu, off);
            mu *= (1.0f / 64.0f);
            const float xm = x - mu;
            float v2 = xm * xm;
#pragma unroll
            for (int off = 32; off; off >>= 1) v2 += __shfl_xor(v2, off);
            v2 *= (1.0f / 64.0f);
            const float xn = xm * rsqrtf(v2 + LN_EPS);
            out[(size_t)n * 64 + c] = fmaxf(xn * gc + btc, 0.0f);
        }
        __syncthreads();
    }
}

extern "C" void kernel_launch(void* const* d_in, const int* in_sizes, int n_in,
                              void* d_out, int out_size, void* d_ws, size_t ws_size,
                              hipStream_t stream) {
    const float* h      = (const float*)d_in[0];
    const int*   src    = (const int*)d_in[1];
    const int*   dst    = (const int*)d_in[2];
    const float* Wn     = (const float*)d_in[3];
    const float* bn     = (const float*)d_in[4];
    const float* att    = (const float*)d_in[5];
    const float* Ws     = (const float*)d_in[6];
    const float* bias   = (const float*)d_in[7];
    const float* gamma_ = (const float*)d_in[8];
    const float* beta_  = (const float*)d_in[9];
    float* out = (float*)d_out;

    char* ws = (char*)d_ws;
    size_t off = 0;
    auto alloc = [&](size_t bytes) { void* p = ws + off; off = (off + bytes + 255) & ~(size_t)255; return p; };
    float* wv      = (float*)alloc((size_t)N_NODES * 256 * 4);  // 51.2 MB
    float* alpha_u = (float*)alloc((size_t)N_NODES * 4 * 4);
    float* alpha_v = (float*)alloc((size_t)N_NODES * 4 * 4);
    int*   deg     = (int*)alloc((size_t)N_NODES * 4);
    int*   rowptr  = (int*)alloc((size_t)(N_NODES + 1) * 4);
    int*   cursor  = (int*)alloc((size_t)N_NODES * 4);
    int*   bsum    = (int*)alloc((size_t)NB_SCAN * 4);
    int*   boff    = (int*)alloc((size_t)NB_SCAN * 4);
    int*   csr_src = (int*)alloc((size_t)N_EDGES * 4);          // 3.2 MB

    hipMemsetAsync(deg, 0, (size_t)N_NODES * 4, stream);

    k1_wv<<<1024, 256, 0, stream>>>(h, Wn, bn, att, wv, alpha_u, alpha_v);
    k_deg<<<(N_EDGES + 255) / 256, 256, 0, stream>>>(dst, deg);
    k_scan1<<<NB_SCAN, 256, 0, stream>>>(deg, rowptr, bsum);
    k_scan2<<<1, 256, 0, stream>>>(bsum, boff);
    k_scan3<<<NB_SCAN, 256, 0, stream>>>(rowptr, boff, cursor);
    k_scatter<<<(N_EDGES + 255) / 256, 256, 0, stream>>>(src, dst, cursor, csr_src);
    k_node<<<4096, 256, 0, stream>>>(rowptr, csr_src, alpha_u, alpha_v, wv, Ws,
                                     bias, h, gamma_, beta_, out);
}

// Round 3
// 558.077 us; speedup vs baseline: 1.8969x; 1.3092x over previous
//
#include <hip/hip_runtime.h>

#define N_NODES 50000
#define N_EDGES 800000
#define NEG_SLOPE 0.2f
#define LN_EPS 1e-5f
#define NB_SCAN 196  // ceil(N_NODES/256)

// ---------------- K1: wv = h @ W_node + b; alpha_u/v[n,h] = <wv[n,h,:], att[h,:]> ----------------
__global__ __launch_bounds__(256) void k1_wv(
    const float* __restrict__ h, const float* __restrict__ Wn,
    const float* __restrict__ bn, const float* __restrict__ att,
    float* __restrict__ wv, float* __restrict__ alpha_u, float* __restrict__ alpha_v)
{
    const int t = threadIdx.x;
    const int w = t >> 6, lane = t & 63;
    float wcol[64];
#pragma unroll
    for (int k = 0; k < 64; ++k) wcol[k] = Wn[k * 256 + t];
    const float bcol = bn[t];
    const float au = att[w * 128 + lane];
    const float av = att[w * 128 + 64 + lane];
    for (int n = blockIdx.x; n < N_NODES; n += gridDim.x) {
        const float* __restrict__ hrow = h + (size_t)n * 64;
        float acc0 = bcol, acc1 = 0.f;
#pragma unroll
        for (int k = 0; k < 64; k += 2) {
            acc0 = fmaf(hrow[k], wcol[k], acc0);
            acc1 = fmaf(hrow[k + 1], wcol[k + 1], acc1);
        }
        float acc = acc0 + acc1;
        wv[(size_t)n * 256 + t] = acc;
        float ru = acc * au, rv = acc * av;
#pragma unroll
        for (int off = 32; off; off >>= 1) {
            ru += __shfl_xor(ru, off);
            rv += __shfl_xor(rv, off);
        }
        if (lane == 0) {
            alpha_u[n * 4 + w] = ru;
            alpha_v[n * 4 + w] = rv;
        }
    }
}

// ---------------- CSR build ----------------
__global__ __launch_bounds__(256) void k_deg(const int* __restrict__ dst, int* __restrict__ deg) {
    int e = blockIdx.x * 256 + threadIdx.x;
    if (e < N_EDGES) atomicAdd(&deg[dst[e]], 1);
}

__device__ __forceinline__ int wave_incl_scan(int x, int lane) {
#pragma unroll
    for (int off = 1; off < 64; off <<= 1) {
        int y = __shfl_up(x, off);
        if (lane >= off) x += y;
    }
    return x;
}

__global__ __launch_bounds__(256) void k_scan1(const int* __restrict__ deg,
                                               int* __restrict__ rowptr, int* __restrict__ bsum) {
    __shared__ int wsum[4];
    const int t = threadIdx.x, lane = t & 63, w = t >> 6;
    const int i = blockIdx.x * 256 + t;
    int x = (i < N_NODES) ? deg[i] : 0;
    int incl = wave_incl_scan(x, lane);
    if (lane == 63) wsum[w] = incl;
    __syncthreads();
    int pre = 0;
    for (int ww = 0; ww < w; ++ww) pre += wsum[ww];
    if (i < N_NODES) rowptr[i] = pre + incl - x;
    if (t == 255) bsum[blockIdx.x] = pre + incl;
}

__global__ __launch_bounds__(256) void k_scan2(const int* __restrict__ bsum, int* __restrict__ boff) {
    __shared__ int wsum[4];
    const int t = threadIdx.x, lane = t & 63, w = t >> 6;
    int x = (t < NB_SCAN) ? bsum[t] : 0;
    int incl = wave_incl_scan(x, lane);
    if (lane == 63) wsum[w] = incl;
    __syncthreads();
    int pre = 0;
    for (int ww = 0; ww < w; ++ww) pre += wsum[ww];
    if (t < NB_SCAN) boff[t] = pre + incl - x;
}

__global__ __launch_bounds__(256) void k_scan3(int* __restrict__ rowptr, const int* __restrict__ boff,
                                               int* __restrict__ cursor) {
    const int i = blockIdx.x * 256 + threadIdx.x;
    if (i < N_NODES) {
        int v = rowptr[i] + boff[blockIdx.x];
        rowptr[i] = v;
        cursor[i] = v;
    }
    if (i == 0) rowptr[N_NODES] = N_EDGES;
}

__global__ __launch_bounds__(256) void k_scatter(const int* __restrict__ src, const int* __restrict__ dst,
                                                 int* __restrict__ cursor, int* __restrict__ csr_src) {
    int e = blockIdx.x * 256 + threadIdx.x;
    if (e < N_EDGES) {
        int pos = atomicAdd(&cursor[dst[e]], 1);
        csr_src[pos] = src[e];
    }
}

// ---------------- fused: per-node online-softmax aggregate + output GEMM + LN ----------------
// one 256-thread block per node; thread t = (head w = t>>6, col c = t&63).
// Edge loop unrolled x8 with clamped indices + (-inf) masking: 8 wv gathers in flight.
__global__ __launch_bounds__(256) void k_node(
    const int* __restrict__ rowptr, const int* __restrict__ csr_src,
    const float* __restrict__ alpha_u, const float* __restrict__ alpha_v,
    const float* __restrict__ wv, const float* __restrict__ Ws,
    const float* __restrict__ bias, const float* __restrict__ h,
    const float* __restrict__ gamma_, const float* __restrict__ beta_,
    float* __restrict__ out)
{
    __shared__ float aggs[256];
    __shared__ float part[256];
    const int t = threadIdx.x;
    const int w = __builtin_amdgcn_readfirstlane(t >> 6);
    const int c = t & 63;
    float wreg[64];
#pragma unroll
    for (int k = 0; k < 64; ++k) wreg[k] = Ws[(size_t)(w * 64 + k) * 64 + c];
    const float bc = bias[c], gc = gamma_[c], btc = beta_[c];

    for (int n = blockIdx.x; n < N_NODES; n += gridDim.x) {
        const int r0 = rowptr[n], r1 = rowptr[n + 1];
        const float avw = alpha_v[n * 4 + w];
        float m = -INFINITY, den = 0.f, acc = 0.f;
        const int rlast = r1 - 1;
        for (int j = r0; j < r1; j += 8) {
            int idx[8];
#pragma unroll
            for (int i = 0; i < 8; ++i) {
                int jj = j + i;
                idx[i] = csr_src[jj < rlast ? jj : rlast];
            }
            float u[8];
#pragma unroll
            for (int i = 0; i < 8; ++i) u[i] = wv[(size_t)idx[i] * 256 + t];
            float lg[8];
#pragma unroll
            for (int i = 0; i < 8; ++i) {
                float l = alpha_u[idx[i] * 4 + w] + avw;
                l = l > 0.f ? l : NEG_SLOPE * l;
                lg[i] = (j + i < r1) ? l : -INFINITY;
            }
            float mx = fmaxf(fmaxf(fmaxf(lg[0], lg[1]), fmaxf(lg[2], lg[3])),
                             fmaxf(fmaxf(lg[4], lg[5]), fmaxf(lg[6], lg[7])));
            if (mx > m) {  // wave-uniform branch
                float r = __expf(m - mx);
                acc *= r;
                den *= r;
                m = mx;
            }
#pragma unroll
            for (int i = 0; i < 8; ++i) {
                float e = __expf(lg[i] - m);
                den += e;
                acc = fmaf(e, u[i], acc);
            }
        }
        const float inv = 1.0f / fmaxf(den, 1e-16f);
        aggs[t] = acc * inv;
        __syncthreads();
        float p = 0.f;
#pragma unroll
        for (int k = 0; k < 64; ++k) p = fmaf(aggs[w * 64 + k], wreg[k], p);
        part[t] = p;
        __syncthreads();
        if (w == 0) {
            float x = part[c] + part[64 + c] + part[128 + c] + part[192 + c] + bc + h[(size_t)n * 64 + c];
            float mu = x;
#pragma unroll
            for (int off = 32; off; off >>= 1) mu += __shfl_xor(mu, off);
            mu *= (1.0f / 64.0f);
            const float xm = x - mu;
            float v2 = xm * xm;
#pragma unroll
            for (int off = 32; off; off >>= 1) v2 += __shfl_xor(v2, off);
            v2 *= (1.0f / 64.0f);
            const float xn = xm * rsqrtf(v2 + LN_EPS);
            out[(size_t)n * 64 + c] = fmaxf(xn * gc + btc, 0.0f);
        }
        __syncthreads();
    }
}

extern "C" void kernel_launch(void* const* d_in, const int* in_sizes, int n_in,
                              void* d_out, int out_size, void* d_ws, size_t ws_size,
                              hipStream_t stream) {
    const float* h      = (const float*)d_in[0];
    const int*   src    = (const int*)d_in[1];
    const int*   dst    = (const int*)d_in[2];
    const float* Wn     = (const float*)d_in[3];
    const float* bn     = (const float*)d_in[4];
    const float* att    = (const float*)d_in[5];
    const float* Ws     = (const float*)d_in[6];
    const float* bias   = (const float*)d_in[7];
    const float* gamma_ = (const float*)d_in[8];
    const float* beta_  = (const float*)d_in[9];
    float* out = (float*)d_out;

    char* ws = (char*)d_ws;
    size_t off = 0;
    auto alloc = [&](size_t bytes) { void* p = ws + off; off = (off + bytes + 255) & ~(size_t)255; return p; };
    float* wv      = (float*)alloc((size_t)N_NODES * 256 * 4);  // 51.2 MB
    float* alpha_u = (float*)alloc((size_t)N_NODES * 4 * 4);
    float* alpha_v = (float*)alloc((size_t)N_NODES * 4 * 4);
    int*   deg     = (int*)alloc((size_t)N_NODES * 4);
    int*   rowptr  = (int*)alloc((size_t)(N_NODES + 1) * 4);
    int*   cursor  = (int*)alloc((size_t)N_NODES * 4);
    int*   bsum    = (int*)alloc((size_t)NB_SCAN * 4);
    int*   boff    = (int*)alloc((size_t)NB_SCAN * 4);
    int*   csr_src = (int*)alloc((size_t)N_EDGES * 4);          // 3.2 MB

    hipMemsetAsync(deg, 0, (size_t)N_NODES * 4, stream);

    k1_wv<<<1024, 256, 0, stream>>>(h, Wn, bn, att, wv, alpha_u, alpha_v);
    k_deg<<<(N_EDGES + 255) / 256, 256, 0, stream>>>(dst, deg);
    k_scan1<<<NB_SCAN, 256, 0, stream>>>(deg, rowptr, bsum);
    k_scan2<<<1, 256, 0, stream>>>(bsum, boff);
    k_scan3<<<NB_SCAN, 256, 0, stream>>>(rowptr, boff, cursor);
    k_scatter<<<(N_EDGES + 255) / 256, 256, 0, stream>>>(src, dst, cursor, csr_src);
    k_node<<<4096, 256, 0, stream>>>(rowptr, csr_src, alpha_u, alpha_v, wv, Ws,
                                     bias, h, gamma_, beta_, out);
}

// Round 4
// 465.720 us; speedup vs baseline: 2.2731x; 1.1983x over previous
//
#include <hip/hip_runtime.h>

#define N_NODES 50000
#define N_EDGES 800000
#define NEG_SLOPE 0.2f
#define LN_EPS 1e-5f
#define NB_SCAN 196  // ceil(N_NODES/256)

// ---------------- K1: wv = h @ W_node + b; alpha_u/v[n,h] = <wv[n,h,:], att[h,:]> ----------------
__global__ __launch_bounds__(256) void k1_wv(
    const float* __restrict__ h, const float* __restrict__ Wn,
    const float* __restrict__ bn, const float* __restrict__ att,
    float* __restrict__ wv, float* __restrict__ alpha_u, float* __restrict__ alpha_v)
{
    const int t = threadIdx.x;
    const int w = t >> 6, lane = t & 63;
    float wcol[64];
#pragma unroll
    for (int k = 0; k < 64; ++k) wcol[k] = Wn[k * 256 + t];
    const float bcol = bn[t];
    const float au = att[w * 128 + lane];
    const float av = att[w * 128 + 64 + lane];
    for (int n = blockIdx.x; n < N_NODES; n += gridDim.x) {
        const float* __restrict__ hrow = h + (size_t)n * 64;
        float acc0 = bcol, acc1 = 0.f;
#pragma unroll
        for (int k = 0; k < 64; k += 2) {
            acc0 = fmaf(hrow[k], wcol[k], acc0);
            acc1 = fmaf(hrow[k + 1], wcol[k + 1], acc1);
        }
        float acc = acc0 + acc1;
        wv[(size_t)n * 256 + t] = acc;
        float ru = acc * au, rv = acc * av;
#pragma unroll
        for (int off = 32; off; off >>= 1) {
            ru += __shfl_xor(ru, off);
            rv += __shfl_xor(rv, off);
        }
        if (lane == 0) {
            alpha_u[n * 4 + w] = ru;
            alpha_v[n * 4 + w] = rv;
        }
    }
}

// ---------------- CSR build ----------------
__global__ __launch_bounds__(256) void k_deg(const int* __restrict__ dst, int* __restrict__ deg) {
    int e = blockIdx.x * 256 + threadIdx.x;
    if (e < N_EDGES) atomicAdd(&deg[dst[e]], 1);
}

__device__ __forceinline__ int wave_incl_scan(int x, int lane) {
#pragma unroll
    for (int off = 1; off < 64; off <<= 1) {
        int y = __shfl_up(x, off);
        if (lane >= off) x += y;
    }
    return x;
}

__global__ __launch_bounds__(256) void k_scan1(const int* __restrict__ deg,
                                               int* __restrict__ rowptr, int* __restrict__ bsum) {
    __shared__ int wsum[4];
    const int t = threadIdx.x, lane = t & 63, w = t >> 6;
    const int i = blockIdx.x * 256 + t;
    int x = (i < N_NODES) ? deg[i] : 0;
    int incl = wave_incl_scan(x, lane);
    if (lane == 63) wsum[w] = incl;
    __syncthreads();
    int pre = 0;
    for (int ww = 0; ww < w; ++ww) pre += wsum[ww];
    if (i < N_NODES) rowptr[i] = pre + incl - x;
    if (t == 255) bsum[blockIdx.x] = pre + incl;
}

__global__ __launch_bounds__(256) void k_scan2(const int* __restrict__ bsum, int* __restrict__ boff) {
    __shared__ int wsum[4];
    const int t = threadIdx.x, lane = t & 63, w = t >> 6;
    int x = (t < NB_SCAN) ? bsum[t] : 0;
    int incl = wave_incl_scan(x, lane);
    if (lane == 63) wsum[w] = incl;
    __syncthreads();
    int pre = 0;
    for (int ww = 0; ww < w; ++ww) pre += wsum[ww];
    if (t < NB_SCAN) boff[t] = pre + incl - x;
}

__global__ __launch_bounds__(256) void k_scan3(int* __restrict__ rowptr, const int* __restrict__ boff,
                                               int* __restrict__ cursor) {
    const int i = blockIdx.x * 256 + threadIdx.x;
    if (i < N_NODES) {
        int v = rowptr[i] + boff[blockIdx.x];
        rowptr[i] = v;
        cursor[i] = v;
    }
    if (i == 0) rowptr[N_NODES] = N_EDGES;
}

__global__ __launch_bounds__(256) void k_scatter(const int* __restrict__ src, const int* __restrict__ dst,
                                                 int* __restrict__ cursor, int* __restrict__ csr_src) {
    int e = blockIdx.x * 256 + threadIdx.x;
    if (e < N_EDGES) {
        int pos = atomicAdd(&cursor[dst[e]], 1);
        csr_src[pos] = src[e];
    }
}

// ---------------- k_agg: ONE WAVE PER NODE, float4 row gathers, online softmax ----------------
// lane l owns cols [4l, 4l+4) of the 256-wide wv row; head of lane = l>>4.
// csr_src reads are wave-uniform -> scalar loads. No barriers. Writes normalized agg row.
__global__ __launch_bounds__(256) void k_agg(
    const int* __restrict__ rowptr, const int* __restrict__ csr_src,
    const float* __restrict__ alpha_u, const float* __restrict__ alpha_v,
    const float* __restrict__ wv, float* __restrict__ agg)
{
    const int lane = threadIdx.x & 63;
    const int hd = lane >> 4;
    const int wid = (blockIdx.x * 256 + threadIdx.x) >> 6;
    const int nwaves = (gridDim.x * 256) >> 6;
    for (int n = wid; n < N_NODES; n += nwaves) {
        const int r0 = rowptr[n], r1 = rowptr[n + 1];
        const float avw = alpha_v[n * 4 + hd];
        float m = -INFINITY, den = 0.f;
        float ax = 0.f, ay = 0.f, az = 0.f, aw = 0.f;
        const int rlast = r1 - 1;
        for (int j = r0; j < r1; j += 8) {
            int idx[8];
#pragma unroll
            for (int i = 0; i < 8; ++i) {
                int jj = j + i;
                idx[i] = csr_src[jj < rlast ? jj : rlast];
            }
            float4 u[8];
#pragma unroll
            for (int i = 0; i < 8; ++i)
                u[i] = *(const float4*)(wv + (size_t)idx[i] * 256 + 4 * lane);
            float lg[8];
#pragma unroll
            for (int i = 0; i < 8; ++i) {
                float l = alpha_u[idx[i] * 4 + hd] + avw;
                l = l > 0.f ? l : NEG_SLOPE * l;
                lg[i] = (j + i < r1) ? l : -INFINITY;
            }
            float mx = fmaxf(fmaxf(fmaxf(lg[0], lg[1]), fmaxf(lg[2], lg[3])),
                             fmaxf(fmaxf(lg[4], lg[5]), fmaxf(lg[6], lg[7])));
            float mn = fmaxf(m, mx);
            float sc = __expf(m - mn);  // first chunk: exp(-inf)=0 (acc,den already 0)
            ax *= sc; ay *= sc; az *= sc; aw *= sc; den *= sc;
            m = mn;
#pragma unroll
            for (int i = 0; i < 8; ++i) {
                float e = __expf(lg[i] - m);
                den += e;
                ax = fmaf(e, u[i].x, ax);
                ay = fmaf(e, u[i].y, ay);
                az = fmaf(e, u[i].z, az);
                aw = fmaf(e, u[i].w, aw);
            }
        }
        const float inv = 1.0f / fmaxf(den, 1e-16f);
        float4 o = make_float4(ax * inv, ay * inv, az * inv, aw * inv);
        *(float4*)(agg + (size_t)n * 256 + 4 * lane) = o;
    }
}

// ---------------- k_out: h_new = agg @ W_scale + bias; x = h_new + h; LN; relu ----------------
// 4 nodes per block-iteration; matvec by all 4 waves (wave w = head w), then wave v LNs node nb+v.
__global__ __launch_bounds__(256) void k_out(
    const float* __restrict__ agg, const float* __restrict__ Ws,
    const float* __restrict__ bias, const float* __restrict__ h,
    const float* __restrict__ gamma_, const float* __restrict__ beta_,
    float* __restrict__ out)
{
    __shared__ float part[4][256];
    const int t = threadIdx.x;
    const int w = t >> 6;   // wave id == head id
    const int c = t & 63;
    float wreg[64];
#pragma unroll
    for (int k = 0; k < 64; ++k) wreg[k] = Ws[(size_t)(w * 64 + k) * 64 + c];
    const float bc = bias[c], gc = gamma_[c], btc = beta_[c];

    for (int nb = blockIdx.x * 4; nb < N_NODES; nb += gridDim.x * 4) {
#pragma unroll
        for (int vv = 0; vv < 4; ++vv) {
            const int n = nb + vv;
            float p = 0.f;
            if (n < N_NODES) {
                const float* __restrict__ arow = agg + (size_t)n * 256 + w * 64;  // wave-uniform -> s_loads
#pragma unroll
                for (int k = 0; k < 64; ++k) p = fmaf(arow[k], wreg[k], p);
            }
            part[vv][t] = p;
        }
        __syncthreads();
        const int n = nb + w;  // wave w finishes node nb+w
        if (n < N_NODES) {
            float x = part[w][c] + part[w][64 + c] + part[w][128 + c] + part[w][192 + c]
                      + bc + h[(size_t)n * 64 + c];
            float mu = x;
#pragma unroll
            for (int off = 32; off; off >>= 1) mu += __shfl_xor(mu, off);
            mu *= (1.0f / 64.0f);
            const float xm = x - mu;
            float v2 = xm * xm;
#pragma unroll
            for (int off = 32; off; off >>= 1) v2 += __shfl_xor(v2, off);
            v2 *= (1.0f / 64.0f);
            const float xn = xm * rsqrtf(v2 + LN_EPS);
            out[(size_t)n * 64 + c] = fmaxf(xn * gc + btc, 0.0f);
        }
        __syncthreads();
    }
}

extern "C" void kernel_launch(void* const* d_in, const int* in_sizes, int n_in,
                              void* d_out, int out_size, void* d_ws, size_t ws_size,
                              hipStream_t stream) {
    const float* h      = (const float*)d_in[0];
    const int*   src    = (const int*)d_in[1];
    const int*   dst    = (const int*)d_in[2];
    const float* Wn     = (const float*)d_in[3];
    const float* bn     = (const float*)d_in[4];
    const float* att    = (const float*)d_in[5];
    const float* Ws     = (const float*)d_in[6];
    const float* bias   = (const float*)d_in[7];
    const float* gamma_ = (const float*)d_in[8];
    const float* beta_  = (const float*)d_in[9];
    float* out = (float*)d_out;

    char* ws = (char*)d_ws;
    size_t off = 0;
    auto alloc = [&](size_t bytes) { void* p = ws + off; off = (off + bytes + 255) & ~(size_t)255; return p; };
    float* wv      = (float*)alloc((size_t)N_NODES * 256 * 4);  // 51.2 MB
    float* agg     = (float*)alloc((size_t)N_NODES * 256 * 4);  // 51.2 MB
    float* alpha_u = (float*)alloc((size_t)N_NODES * 4 * 4);
    float* alpha_v = (float*)alloc((size_t)N_NODES * 4 * 4);
    int*   deg     = (int*)alloc((size_t)N_NODES * 4);
    int*   rowptr  = (int*)alloc((size_t)(N_NODES + 1) * 4);
    int*   cursor  = (int*)alloc((size_t)N_NODES * 4);
    int*   bsum    = (int*)alloc((size_t)NB_SCAN * 4);
    int*   boff    = (int*)alloc((size_t)NB_SCAN * 4);
    int*   csr_src = (int*)alloc((size_t)N_EDGES * 4);          // 3.2 MB

    hipMemsetAsync(deg, 0, (size_t)N_NODES * 4, stream);

    k1_wv<<<1024, 256, 0, stream>>>(h, Wn, bn, att, wv, alpha_u, alpha_v);
    k_deg<<<(N_EDGES + 255) / 256, 256, 0, stream>>>(dst, deg);
    k_scan1<<<NB_SCAN, 256, 0, stream>>>(deg, rowptr, bsum);
    k_scan2<<<1, 256, 0, stream>>>(bsum, boff);
    k_scan3<<<NB_SCAN, 256, 0, stream>>>(rowptr, boff, cursor);
    k_scatter<<<(N_EDGES + 255) / 256, 256, 0, stream>>>(src, dst, cursor, csr_src);
    k_agg<<<4096, 256, 0, stream>>>(rowptr, csr_src, alpha_u, alpha_v, wv, agg);
    k_out<<<2048, 256, 0, stream>>>(agg, Ws, bias, h, gamma_, beta_, out);
}

// Round 5
// 328.292 us; speedup vs baseline: 3.2247x; 1.4186x over previous
//
#include <hip/hip_runtime.h>
#include <hip/hip_fp16.h>

#define N_NODES 50000
#define N_EDGES 800000
#define NEG_SLOPE 0.2f
#define LN_EPS 1e-5f
#define NB_SCAN 196  // ceil(N_NODES/256)

// ---------------- K1: wv = h @ W_node + b (fp16 out); alpha_u/v[n,h] = <wv, att[h]> (f32) ----
// __launch_bounds__(256,2): cap 2 wg/CU -> up to 256 VGPR so wcol[64] stays register-resident.
__global__ __launch_bounds__(256, 2) void k1_wv(
    const float* __restrict__ h, const float* __restrict__ Wn,
    const float* __restrict__ bn, const float* __restrict__ att,
    __half* __restrict__ wv, float* __restrict__ alpha_u, float* __restrict__ alpha_v)
{
    const int t = threadIdx.x;
    const int w = t >> 6, lane = t & 63;
    float wcol[64];
#pragma unroll
    for (int k = 0; k < 64; ++k) wcol[k] = Wn[k * 256 + t];
    const float bcol = bn[t];
    const float au = att[w * 128 + lane];
    const float av = att[w * 128 + 64 + lane];
    for (int n = blockIdx.x; n < N_NODES; n += gridDim.x) {
        const float* __restrict__ hrow = h + (size_t)n * 64;  // wave-uniform -> s_loads
        float acc0 = bcol, acc1 = 0.f;
#pragma unroll
        for (int k = 0; k < 64; k += 2) {
            acc0 = fmaf(hrow[k], wcol[k], acc0);
            acc1 = fmaf(hrow[k + 1], wcol[k + 1], acc1);
        }
        float acc = acc0 + acc1;
        wv[(size_t)n * 256 + t] = __float2half(acc);
        float ru = acc * au, rv = acc * av;
#pragma unroll
        for (int off = 32; off; off >>= 1) {
            ru += __shfl_xor(ru, off);
            rv += __shfl_xor(rv, off);
        }
        if (lane == 0) {
            alpha_u[n * 4 + w] = ru;
            alpha_v[n * 4 + w] = rv;
        }
    }
}

// ---------------- CSR build ----------------
__global__ __launch_bounds__(256) void k_deg(const int* __restrict__ dst, int* __restrict__ deg) {
    int e = blockIdx.x * 256 + threadIdx.x;
    if (e < N_EDGES) atomicAdd(&deg[dst[e]], 1);
}

__device__ __forceinline__ int wave_incl_scan(int x, int lane) {
#pragma unroll
    for (int off = 1; off < 64; off <<= 1) {
        int y = __shfl_up(x, off);
        if (lane >= off) x += y;
    }
    return x;
}

__global__ __launch_bounds__(256) void k_scan1(const int* __restrict__ deg,
                                               int* __restrict__ rowptr, int* __restrict__ bsum) {
    __shared__ int wsum[4];
    const int t = threadIdx.x, lane = t & 63, w = t >> 6;
    const int i = blockIdx.x * 256 + t;
    int x = (i < N_NODES) ? deg[i] : 0;
    int incl = wave_incl_scan(x, lane);
    if (lane == 63) wsum[w] = incl;
    __syncthreads();
    int pre = 0;
    for (int ww = 0; ww < w; ++ww) pre += wsum[ww];
    if (i < N_NODES) rowptr[i] = pre + incl - x;
    if (t == 255) bsum[blockIdx.x] = pre + incl;
}

__global__ __launch_bounds__(256) void k_scan2(const int* __restrict__ bsum, int* __restrict__ boff) {
    __shared__ int wsum[4];
    const int t = threadIdx.x, lane = t & 63, w = t >> 6;
    int x = (t < NB_SCAN) ? bsum[t] : 0;
    int incl = wave_incl_scan(x, lane);
    if (lane == 63) wsum[w] = incl;
    __syncthreads();
    int pre = 0;
    for (int ww = 0; ww < w; ++ww) pre += wsum[ww];
    if (t < NB_SCAN) boff[t] = pre + incl - x;
}

__global__ __launch_bounds__(256) void k_scan3(int* __restrict__ rowptr, const int* __restrict__ boff,
                                               int* __restrict__ cursor) {
    const int i = blockIdx.x * 256 + threadIdx.x;
    if (i < N_NODES) {
        int v = rowptr[i] + boff[blockIdx.x];
        rowptr[i] = v;
        cursor[i] = v;
    }
    if (i == 0) rowptr[N_NODES] = N_EDGES;
}

__global__ __launch_bounds__(256) void k_scatter(const int* __restrict__ src, const int* __restrict__ dst,
                                                 int* __restrict__ cursor, int* __restrict__ csr_src) {
    int e = blockIdx.x * 256 + threadIdx.x;
    if (e < N_EDGES) {
        int pos = atomicAdd(&cursor[dst[e]], 1);
        csr_src[pos] = src[e];
    }
}

// ---------------- k_agg: one wave per node, fp16 row gathers (8B/lane), online softmax ----------
__global__ __launch_bounds__(256) void k_agg(
    const int* __restrict__ rowptr, const int* __restrict__ csr_src,
    const float* __restrict__ alpha_u, const float* __restrict__ alpha_v,
    const __half* __restrict__ wv, float* __restrict__ agg)
{
    const int lane = threadIdx.x & 63;
    const int hd = lane >> 4;
    const int wid = (blockIdx.x * 256 + threadIdx.x) >> 6;
    const int nwaves = (gridDim.x * 256) >> 6;
    for (int n = wid; n < N_NODES; n += nwaves) {
        const int r0 = rowptr[n], r1 = rowptr[n + 1];
        const float avw = alpha_v[n * 4 + hd];
        float m = -INFINITY, den = 0.f;
        float ax = 0.f, ay = 0.f, az = 0.f, aw = 0.f;
        const int rlast = r1 - 1;
        for (int j = r0; j < r1; j += 8) {
            int idx[8];
#pragma unroll
            for (int i = 0; i < 8; ++i) {
                int jj = j + i;
                idx[i] = csr_src[jj < rlast ? jj : rlast];
            }
            uint2 raw[8];
#pragma unroll
            for (int i = 0; i < 8; ++i)
                raw[i] = *(const uint2*)(wv + ((size_t)idx[i] << 8) + 4 * lane);
            float lg[8];
#pragma unroll
            for (int i = 0; i < 8; ++i) {
                float l = alpha_u[idx[i] * 4 + hd] + avw;
                l = l > 0.f ? l : NEG_SLOPE * l;
                lg[i] = (j + i < r1) ? l : -INFINITY;
            }
            float mx = fmaxf(fmaxf(fmaxf(lg[0], lg[1]), fmaxf(lg[2], lg[3])),
                             fmaxf(fmaxf(lg[4], lg[5]), fmaxf(lg[6], lg[7])));
            float mn = fmaxf(m, mx);
            float sc = __expf(m - mn);  // first chunk: exp(-inf)=0 (acc,den already 0)
            ax *= sc; ay *= sc; az *= sc; aw *= sc; den *= sc;
            m = mn;
#pragma unroll
            for (int i = 0; i < 8; ++i) {
                float e = __expf(lg[i] - m);
                den += e;
                float2 f0 = __half22float2(*(const __half2*)&raw[i].x);
                float2 f1 = __half22float2(*(const __half2*)&raw[i].y);
                ax = fmaf(e, f0.x, ax);
                ay = fmaf(e, f0.y, ay);
                az = fmaf(e, f1.x, az);
                aw = fmaf(e, f1.y, aw);
            }
        }
        const float inv = 1.0f / fmaxf(den, 1e-16f);
        float4 o = make_float4(ax * inv, ay * inv, az * inv, aw * inv);
        *(float4*)(agg + (size_t)n * 256 + 4 * lane) = o;
    }
}

// ---------------- k_out: h_new = agg @ W_scale + bias; x = h_new + h; LN; relu ----------------
// 8 nodes per block-iteration staged into LDS (coalesced float4); wreg[64] register-resident
// via __launch_bounds__(256,2); matvec reads aggs via broadcast ds_read_b128.
__global__ __launch_bounds__(256, 2) void k_out(
    const float* __restrict__ agg, const float* __restrict__ Ws,
    const float* __restrict__ bias, const float* __restrict__ h,
    const float* __restrict__ gamma_, const float* __restrict__ beta_,
    float* __restrict__ out)
{
    __shared__ float aggs[8][256];
    __shared__ float part[8][4][64];
    const int t = threadIdx.x;
    const int w = t >> 6;   // wave id == head id (k-slice)
    const int c = t & 63;
    float wreg[64];
#pragma unroll
    for (int k = 0; k < 64; ++k) wreg[k] = Ws[(size_t)(w * 64 + k) * 64 + c];
    const float bc = bias[c], gc = gamma_[c], btc = beta_[c];

    // N_NODES % 8 == 0 -> no tail guards
    for (int nb = blockIdx.x * 8; nb < N_NODES; nb += gridDim.x * 8) {
#pragma unroll
        for (int i = 0; i < 2; ++i) {
            int f = i * 256 + t;                 // float4 index in [0,512)
            int node = f >> 6, col4 = f & 63;
            float4 v = *(const float4*)(agg + (size_t)(nb + node) * 256 + col4 * 4);
            *(float4*)&aggs[node][col4 * 4] = v;
        }
        __syncthreads();
#pragma unroll
        for (int n = 0; n < 8; ++n) {
            float p = 0.f;
#pragma unroll
            for (int k4 = 0; k4 < 16; ++k4) {
                float4 av = *(const float4*)&aggs[n][w * 64 + k4 * 4];  // broadcast read
                p = fmaf(av.x, wreg[k4 * 4 + 0], p);
                p = fmaf(av.y, wreg[k4 * 4 + 1], p);
                p = fmaf(av.z, wreg[k4 * 4 + 2], p);
                p = fmaf(av.w, wreg[k4 * 4 + 3], p);
            }
            part[n][w][c] = p;
        }
        __syncthreads();
#pragma unroll
        for (int i = 0; i < 2; ++i) {
            const int n = w + i * 4;        // wave w finishes nodes nb+w, nb+w+4
            const int gn = nb + n;
            float x = part[n][0][c] + part[n][1][c] + part[n][2][c] + part[n][3][c]
                      + bc + h[(size_t)gn * 64 + c];
            float mu = x;
#pragma unroll
            for (int off = 32; off; off >>= 1) mu += __shfl_xor(mu, off);
            mu *= (1.0f / 64.0f);
            const float xm = x - mu;
            float v2 = xm * xm;
#pragma unroll
            for (int off = 32; off; off >>= 1) v2 += __shfl_xor(v2, off);
            v2 *= (1.0f / 64.0f);
            const float xn = xm * rsqrtf(v2 + LN_EPS);
            out[(size_t)gn * 64 + c] = fmaxf(xn * gc + btc, 0.0f);
        }
        __syncthreads();
    }
}

extern "C" void kernel_launch(void* const* d_in, const int* in_sizes, int n_in,
                              void* d_out, int out_size, void* d_ws, size_t ws_size,
                              hipStream_t stream) {
    const float* h      = (const float*)d_in[0];
    const int*   src    = (const int*)d_in[1];
    const int*   dst    = (const int*)d_in[2];
    const float* Wn     = (const float*)d_in[3];
    const float* bn     = (const float*)d_in[4];
    const float* att    = (const float*)d_in[5];
    const float* Ws     = (const float*)d_in[6];
    const float* bias   = (const float*)d_in[7];
    const float* gamma_ = (const float*)d_in[8];
    const float* beta_  = (const float*)d_in[9];
    float* out = (float*)d_out;

    char* ws = (char*)d_ws;
    size_t off = 0;
    auto alloc = [&](size_t bytes) { void* p = ws + off; off = (off + bytes + 255) & ~(size_t)255; return p; };
    __half* wv     = (__half*)alloc((size_t)N_NODES * 256 * 2);  // 25.6 MB (fp16)
    float* agg     = (float*)alloc((size_t)N_NODES * 256 * 4);   // 51.2 MB
    float* alpha_u = (float*)alloc((size_t)N_NODES * 4 * 4);
    float* alpha_v = (float*)alloc((size_t)N_NODES * 4 * 4);
    int*   deg     = (int*)alloc((size_t)N_NODES * 4);
    int*   rowptr  = (int*)alloc((size_t)(N_NODES + 1) * 4);
    int*   cursor  = (int*)alloc((size_t)N_NODES * 4);
    int*   bsum    = (int*)alloc((size_t)NB_SCAN * 4);
    int*   boff    = (int*)alloc((size_t)NB_SCAN * 4);
    int*   csr_src = (int*)alloc((size_t)N_EDGES * 4);           // 3.2 MB

    hipMemsetAsync(deg, 0, (size_t)N_NODES * 4, stream);

    k1_wv<<<1024, 256, 0, stream>>>(h, Wn, bn, att, wv, alpha_u, alpha_v);
    k_deg<<<(N_EDGES + 255) / 256, 256, 0, stream>>>(dst, deg);
    k_scan1<<<NB_SCAN, 256, 0, stream>>>(deg, rowptr, bsum);
    k_scan2<<<1, 256, 0, stream>>>(bsum, boff);
    k_scan3<<<NB_SCAN, 256, 0, stream>>>(rowptr, boff, cursor);
    k_scatter<<<(N_EDGES + 255) / 256, 256, 0, stream>>>(src, dst, cursor, csr_src);
    k_agg<<<4096, 256, 0, stream>>>(rowptr, csr_src, alpha_u, alpha_v, wv, agg);
    k_out<<<2048, 256, 0, stream>>>(agg, Ws, bias, h, gamma_, beta_, out);
}

// Round 7
// 300.397 us; speedup vs baseline: 3.5241x; 1.0929x over previous
//
#include <hip/hip_runtime.h>
#include <hip/hip_fp16.h>

#define N_NODES 50000
#define N_EDGES 800000
#define NEG_SLOPE 0.2f
#define LN_EPS 1e-5f
#define NB_SCAN 196   // ceil(N_NODES/256)
#define K1_BLOCKS 1536
#define DEG_BLOCKS 3125  // ceil(N_EDGES/256)

// ---------------- fused front: [blocks 0..K1_BLOCKS) GEMM+alpha, rest: degree+rank ----------------
// k1 part: wv = h @ W_node + b (fp16 out); alpha_u/v[n,h] = <wv, att[h]> (f32).
// (256,3): VGPR cap ~168 so wcol[64] stays register-resident, 3 blocks/CU.
__global__ __launch_bounds__(256, 3) void k_front(
    const float* __restrict__ h, const float* __restrict__ Wn,
    const float* __restrict__ bn, const float* __restrict__ att,
    const int* __restrict__ dst,
    __half* __restrict__ wv, float* __restrict__ alpha_u, float* __restrict__ alpha_v,
    int* __restrict__ deg, int* __restrict__ rank)
{
    const int t = threadIdx.x;
    if (blockIdx.x >= K1_BLOCKS) {
        // degree histogram + per-edge rank within destination
        int e = (blockIdx.x - K1_BLOCKS) * 256 + t;
        if (e < N_EDGES) rank[e] = atomicAdd(&deg[dst[e]], 1);
        return;
    }
    const int w = t >> 6, lane = t & 63;
    float wcol[64];
#pragma unroll
    for (int k = 0; k < 64; ++k) wcol[k] = Wn[k * 256 + t];
    const float bcol = bn[t];
    const float au = att[w * 128 + lane];
    const float av = att[w * 128 + 64 + lane];
    for (int n = blockIdx.x; n < N_NODES; n += K1_BLOCKS) {
        const float* __restrict__ hrow = h + (size_t)n * 64;  // wave-uniform -> scalar loads
        float acc0 = bcol, acc1 = 0.f;
#pragma unroll
        for (int k = 0; k < 64; k += 2) {
            acc0 = fmaf(hrow[k], wcol[k], acc0);
            acc1 = fmaf(hrow[k + 1], wcol[k + 1], acc1);
        }
        float acc = acc0 + acc1;
        wv[(size_t)n * 256 + t] = __float2half(acc);
        float ru = acc * au, rv = acc * av;
#pragma unroll
        for (int off = 32; off; off >>= 1) {
            ru += __shfl_xor(ru, off);
            rv += __shfl_xor(rv, off);
        }
        if (lane == 0) {
            alpha_u[n * 4 + w] = ru;
            alpha_v[n * 4 + w] = rv;
        }
    }
}

// ---------------- scan (3 small stages) ----------------
__device__ __forceinline__ int wave_incl_scan(int x, int lane) {
#pragma unroll
    for (int off = 1; off < 64; off <<= 1) {
        int y = __shfl_up(x, off);
        if (lane >= off) x += y;
    }
    return x;
}

__global__ __launch_bounds__(256) void k_scan1(const int* __restrict__ deg,
                                               int* __restrict__ rowptr, int* __restrict__ bsum) {
    __shared__ int wsum[4];
    const int t = threadIdx.x, lane = t & 63, w = t >> 6;
    const int i = blockIdx.x * 256 + t;
    int x = (i < N_NODES) ? deg[i] : 0;
    int incl = wave_incl_scan(x, lane);
    if (lane == 63) wsum[w] = incl;
    __syncthreads();
    int pre = 0;
    for (int ww = 0; ww < w; ++ww) pre += wsum[ww];
    if (i < N_NODES) rowptr[i] = pre + incl - x;
    if (t == 255) bsum[blockIdx.x] = pre + incl;
}

__global__ __launch_bounds__(256) void k_scan2(const int* __restrict__ bsum, int* __restrict__ boff) {
    __shared__ int wsum[4];
    const int t = threadIdx.x, lane = t & 63, w = t >> 6;
    int x = (t < NB_SCAN) ? bsum[t] : 0;
    int incl = wave_incl_scan(x, lane);
    if (lane == 63) wsum[w] = incl;
    __syncthreads();
    int pre = 0;
    for (int ww = 0; ww < w; ++ww) pre += wsum[ww];
    if (t < NB_SCAN) boff[t] = pre + incl - x;
}

__global__ __launch_bounds__(256) void k_scan3(int* __restrict__ rowptr, const int* __restrict__ boff) {
    const int i = blockIdx.x * 256 + threadIdx.x;
    if (i < N_NODES) rowptr[i] += boff[blockIdx.x];
    if (i == 0) rowptr[N_NODES] = N_EDGES;
}

// ---------------- scatter: atomic-free via precomputed rank ----------------
__global__ __launch_bounds__(256) void k_scatter(const int* __restrict__ src, const int* __restrict__ dst,
                                                 const int* __restrict__ rowptr, const int* __restrict__ rank,
                                                 int* __restrict__ csr_src) {
    int e = blockIdx.x * 256 + threadIdx.x;
    if (e < N_EDGES) csr_src[rowptr[dst[e]] + rank[e]] = src[e];
}

// ---------------- k_agg: one wave per node, fp16 row gathers (8B/lane), online softmax ----------
// node range [n0,n1) so it can be split into two dispatches (profiling visibility).
__global__ __launch_bounds__(256) void k_agg(
    const int* __restrict__ rowptr, const int* __restrict__ csr_src,
    const float* __restrict__ alpha_u, const float* __restrict__ alpha_v,
    const __half* __restrict__ wv, float* __restrict__ agg, int n0, int n1)
{
    const int lane = threadIdx.x & 63;
    const int hd = lane >> 4;
    const int wid = (blockIdx.x * 256 + threadIdx.x) >> 6;
    const int nwaves = (gridDim.x * 256) >> 6;
    for (int n = n0 + wid; n < n1; n += nwaves) {
        const int r0 = rowptr[n], r1 = rowptr[n + 1];
        const float avw = alpha_v[n * 4 + hd];
        float m = -INFINITY, den = 0.f;
        float ax = 0.f, ay = 0.f, az = 0.f, aw = 0.f;
        const int rlast = r1 - 1;
        for (int j = r0; j < r1; j += 8) {
            int idx[8];
#pragma unroll
            for (int i = 0; i < 8; ++i) {
                int jj = j + i;
                idx[i] = csr_src[jj < rlast ? jj : rlast];
            }
            uint2 raw[8];
#pragma unroll
            for (int i = 0; i < 8; ++i)
                raw[i] = *(const uint2*)(wv + ((size_t)idx[i] << 8) + 4 * lane);
            float lg[8];
#pragma unroll
            for (int i = 0; i < 8; ++i) {
                float l = alpha_u[idx[i] * 4 + hd] + avw;
                l = l > 0.f ? l : NEG_SLOPE * l;
                lg[i] = (j + i < r1) ? l : -INFINITY;
            }
            float mx = fmaxf(fmaxf(fmaxf(lg[0], lg[1]), fmaxf(lg[2], lg[3])),
                             fmaxf(fmaxf(lg[4], lg[5]), fmaxf(lg[6], lg[7])));
            float mn = fmaxf(m, mx);
            float sc = __expf(m - mn);  // first chunk: exp(-inf)=0 (acc,den already 0)
            ax *= sc; ay *= sc; az *= sc; aw *= sc; den *= sc;
            m = mn;
#pragma unroll
            for (int i = 0; i < 8; ++i) {
                float e = __expf(lg[i] - m);
                den += e;
                float2 f0 = __half22float2(*(const __half2*)&raw[i].x);
                float2 f1 = __half22float2(*(const __half2*)&raw[i].y);
                ax = fmaf(e, f0.x, ax);
                ay = fmaf(e, f0.y, ay);
                az = fmaf(e, f1.x, az);
                aw = fmaf(e, f1.y, aw);
            }
        }
        const float inv = 1.0f / fmaxf(den, 1e-16f);
        float4 o = make_float4(ax * inv, ay * inv, az * inv, aw * inv);
        *(float4*)(agg + (size_t)n * 256 + 4 * lane) = o;
    }
}

// ---------------- k_out: h_new = agg @ W_scale + bias; x = h_new + h; LN; relu ----------------
__global__ __launch_bounds__(256, 3) void k_out(
    const float* __restrict__ agg, const float* __restrict__ Ws,
    const float* __restrict__ bias, const float* __restrict__ h,
    const float* __restrict__ gamma_, const float* __restrict__ beta_,
    float* __restrict__ out)
{
    __shared__ float aggs[8][256];
    __shared__ float part[8][4][64];
    const int t = threadIdx.x;
    const int w = t >> 6;   // wave id == head id (k-slice)
    const int c = t & 63;
    float wreg[64];
#pragma unroll
    for (int k = 0; k < 64; ++k) wreg[k] = Ws[(size_t)(w * 64 + k) * 64 + c];
    const float bc = bias[c], gc = gamma_[c], btc = beta_[c];

    // N_NODES % 8 == 0 -> no tail guards
    for (int nb = blockIdx.x * 8; nb < N_NODES; nb += gridDim.x * 8) {
#pragma unroll
        for (int i = 0; i < 2; ++i) {
            int f = i * 256 + t;                 // float4 index in [0,512)
            int node = f >> 6, col4 = f & 63;
            float4 v = *(const float4*)(agg + (size_t)(nb + node) * 256 + col4 * 4);
            *(float4*)&aggs[node][col4 * 4] = v;
        }
        __syncthreads();
#pragma unroll
        for (int n = 0; n < 8; ++n) {
            float p = 0.f;
#pragma unroll
            for (int k4 = 0; k4 < 16; ++k4) {
                float4 av = *(const float4*)&aggs[n][w * 64 + k4 * 4];  // broadcast read
                p = fmaf(av.x, wreg[k4 * 4 + 0], p);
                p = fmaf(av.y, wreg[k4 * 4 + 1], p);
                p = fmaf(av.z, wreg[k4 * 4 + 2], p);
                p = fmaf(av.w, wreg[k4 * 4 + 3], p);
            }
            part[n][w][c] = p;
        }
        __syncthreads();
#pragma unroll
        for (int i = 0; i < 2; ++i) {
            const int n = w + i * 4;        // wave w finishes nodes nb+w, nb+w+4
            const int gn = nb + n;
            float x = part[n][0][c] + part[n][1][c] + part[n][2][c] + part[n][3][c]
                      + bc + h[(size_t)gn * 64 + c];
            float mu = x;
#pragma unroll
            for (int off = 32; off; off >>= 1) mu += __shfl_xor(mu, off);
            mu *= (1.0f / 64.0f);
            const float xm = x - mu;
            float v2 = xm * xm;
#pragma unroll
            for (int off = 32; off; off >>= 1) v2 += __shfl_xor(v2, off);
            v2 *= (1.0f / 64.0f);
            const float xn = xm * rsqrtf(v2 + LN_EPS);
            out[(size_t)gn * 64 + c] = fmaxf(xn * gc + btc, 0.0f);
        }
        __syncthreads();
    }
}

extern "C" void kernel_launch(void* const* d_in, const int* in_sizes, int n_in,
                              void* d_out, int out_size, void* d_ws, size_t ws_size,
                              hipStream_t stream) {
    const float* h      = (const float*)d_in[0];
    const int*   src    = (const int*)d_in[1];
    const int*   dst    = (const int*)d_in[2];
    const float* Wn     = (const float*)d_in[3];
    const float* bn     = (const float*)d_in[4];
    const float* att    = (const float*)d_in[5];
    const float* Ws     = (const float*)d_in[6];
    const float* bias   = (const float*)d_in[7];
    const float* gamma_ = (const float*)d_in[8];
    const float* beta_  = (const float*)d_in[9];
    float* out = (float*)d_out;

    char* ws = (char*)d_ws;
    size_t off = 0;
    auto alloc = [&](size_t bytes) { void* p = ws + off; off = (off + bytes + 255) & ~(size_t)255; return p; };
    __half* wv     = (__half*)alloc((size_t)N_NODES * 256 * 2);  // 25.6 MB (fp16)
    float* agg     = (float*)alloc((size_t)N_NODES * 256 * 4);   // 51.2 MB
    float* alpha_u = (float*)alloc((size_t)N_NODES * 4 * 4);
    float* alpha_v = (float*)alloc((size_t)N_NODES * 4 * 4);
    int*   deg     = (int*)alloc((size_t)N_NODES * 4);
    int*   rowptr  = (int*)alloc((size_t)(N_NODES + 1) * 4);
    int*   rank    = (int*)alloc((size_t)N_EDGES * 4);           // 3.2 MB
    int*   bsum    = (int*)alloc((size_t)NB_SCAN * 4);
    int*   boff    = (int*)alloc((size_t)NB_SCAN * 4);
    int*   csr_src = (int*)alloc((size_t)N_EDGES * 4);           // 3.2 MB

    hipMemsetAsync(deg, 0, (size_t)N_NODES * 4, stream);

    k_front<<<K1_BLOCKS + DEG_BLOCKS, 256, 0, stream>>>(h, Wn, bn, att, dst,
                                                        wv, alpha_u, alpha_v, deg, rank);
    k_scan1<<<NB_SCAN, 256, 0, stream>>>(deg, rowptr, bsum);
    k_scan2<<<1, 256, 0, stream>>>(bsum, boff);
    k_scan3<<<NB_SCAN, 256, 0, stream>>>(rowptr, boff);
    k_scatter<<<DEG_BLOCKS, 256, 0, stream>>>(src, dst, rowptr, rank, csr_src);
    k_agg<<<2048, 256, 0, stream>>>(rowptr, csr_src, alpha_u, alpha_v, wv, agg, 0, N_NODES / 2);
    k_agg<<<2048, 256, 0, stream>>>(rowptr, csr_src, alpha_u, alpha_v, wv, agg, N_NODES / 2, N_NODES);
    k_out<<<2048, 256, 0, stream>>>(agg, Ws, bias, h, gamma_, beta_, out);
}